// Round 1
// 220.355 us; speedup vs baseline: 1.0475x; 1.0475x over previous
//
#include <hip/hip_runtime.h>
#include <cstdint>
#include <math.h>

#define B_   8
#define S_   1024
#define D_   1024
#define NH_  16
#define NKV_ 8
#define HD_  64
#define M_   (B_*S_)   // 8192 tokens

using bf16   = __bf16;
using bf16x4 = __attribute__((ext_vector_type(4))) __bf16;
using bf16x8 = __attribute__((ext_vector_type(8))) __bf16;
using f32x4  = __attribute__((ext_vector_type(4))) float;

// ---------------- async global->LDS, width 16 (m97 idiom) ----------------
__device__ __forceinline__ void gll16(const bf16* g, const bf16* l) {
    __builtin_amdgcn_global_load_lds(
        (const __attribute__((address_space(1))) unsigned int*)(uintptr_t)g,
        (__attribute__((address_space(3))) unsigned int*)(uintptr_t)l,
        16, 0, 0);
}

// counted-vmcnt + raw-barrier helpers (T3/T4). Fences stop the compiler from
// moving memory ops across the barrier (rule #18-adjacent hazard).
__device__ __forceinline__ void vm_wait0()  { asm volatile("s_waitcnt vmcnt(0)" ::: "memory"); }
__device__ __forceinline__ void bar()       { __builtin_amdgcn_s_barrier(); asm volatile("" ::: "memory"); }

// ---------------- f32 -> bf16 elementwise ----------------
__global__ void k_cvt_bf16(const float* __restrict__ in, bf16* __restrict__ out, int n4) {
    int i = blockIdx.x * blockDim.x + threadIdx.x;
    if (i < n4) {
        float4 v = ((const float4*)in)[i];
        bf16x4 o = { (bf16)v.x, (bf16)v.y, (bf16)v.z, (bf16)v.w };
        ((bf16x4*)out)[i] = o;
    }
}

// ---------------- all 4 weight transposes in one launch: f32 [R][C] -> bf16 [C][R] ----------------
__global__ void k_transpose_all(const float* __restrict__ wq, const float* __restrict__ wk,
                                const float* __restrict__ wv, const float* __restrict__ wo,
                                bf16* __restrict__ wqkvT, bf16* __restrict__ woT) {
    __shared__ float tile[64 * 65];
    const int R = 1024;
    int bx = blockIdx.x;                    // 0..47: wq 16, wk 8, wv 8, wo 16 col-tiles
    const float* in; bf16* out; int C, xo;
    if (bx < 16)      { in = wq; out = wqkvT;               C = 1024; xo = bx; }
    else if (bx < 24) { in = wk; out = wqkvT + 1024 * 1024; C = 512;  xo = bx - 16; }
    else if (bx < 32) { in = wv; out = wqkvT + 1536 * 1024; C = 512;  xo = bx - 24; }
    else              { in = wo; out = woT;                 C = 1024; xo = bx - 32; }
    int r0 = blockIdx.y * 64, c0 = xo * 64;
    int t = threadIdx.x;
    #pragma unroll
    for (int it = 0; it < 16; ++it) {
        int idx = it * 256 + t;
        int r = idx >> 6, c = idx & 63;
        tile[r * 65 + c] = in[(size_t)(r0 + r) * C + c0 + c];
    }
    __syncthreads();
    #pragma unroll
    for (int it = 0; it < 16; ++it) {
        int idx = it * 256 + t;
        int c = idx >> 6, r = idx & 63;
        out[(size_t)(c0 + c) * R + r0 + r] = (bf16)tile[r * 65 + c];
    }
}

// ---------------- 256-wide GEMM: C[M,N] = A[M,K] * Bt[N,K]^T ----------------
// 256xBN tile, BK=64, 8 waves (2M x 4N), per-wave 128 x (BN/4) output.
// Double-buffered LDS (A 64KB + B 2*BN*64*2B). Issue-early staging: next
// tile's gll16 go out BEFORE this tile's 64 MFMAs (~2000cy window >> load
// latency), so the vmcnt drain at tile end is ~free -- removes the
// stage-then-drain stall that capped the 128^2 kernel at ~670 TF.
// XOR chunk swizzle (proven conflict-free in previous rounds) kept.
template <typename OutT, int BN>
__global__ __launch_bounds__(512, 2) void k_gemm256(const bf16* __restrict__ A,
                                                    const bf16* __restrict__ Bt,
                                                    OutT* __restrict__ C, int M, int N, int K) {
    constexpr int NI = BN / 64;            // n-frags per wave
    constexpr int NB = (BN * 8) / 512;     // B gll16 per thread per tile
    __shared__ __align__(16) bf16 aLds[2 * 256 * 64];
    __shared__ __align__(16) bf16 bLds[2 * BN * 64];
    const int t    = threadIdx.x;
    const int lane = t & 63;
    const int w    = t >> 6;
    const int quad = lane >> 4;
    const int l16  = lane & 15;
    const int wr   = w >> 2;               // 0..1  (M)
    const int wc   = w & 3;                // 0..3  (N)
    const int m0 = blockIdx.y * 256;
    const int n0 = blockIdx.x * BN;

    f32x4 acc[8][NI] = {};

    auto stage = [&](int kb, int buf) {
        const int k0 = kb << 6;
        #pragma unroll
        for (int it = 0; it < 4; ++it) {   // A: 256 rows x 8 chunks = 2048 / 512thr
            int ci = it * 512 + t;
            int r = ci >> 3, c = ci & 7;
            int cg = c ^ (r & 7);          // slot c of row r holds global chunk c^(r&7)
            gll16(A + (size_t)(m0 + r) * K + k0 + cg * 8, aLds + buf * (256 * 64) + ci * 8);
        }
        #pragma unroll
        for (int it = 0; it < NB; ++it) {  // B: BN rows x 8 chunks
            int ci = it * 512 + t;
            int r = ci >> 3, c = ci & 7;
            int cg = c ^ (r & 7);
            gll16(Bt + (size_t)(n0 + r) * K + k0 + cg * 8, bLds + buf * (BN * 64) + ci * 8);
        }
    };

    const int NT = K >> 6;
    stage(0, 0);
    vm_wait0();
    bar();

    for (int T = 0; T < NT; ++T) {
        const int buf = T & 1;
        if (T + 1 < NT) stage(T + 1, buf ^ 1);   // issue-early into the slot freed last barrier

        const bf16* aL = aLds + buf * (256 * 64);
        const bf16* bL = bLds + buf * (BN * 64);
        #pragma unroll
        for (int kk = 0; kk < 2; ++kk) {
            bf16x8 af[8], bfr[NI];
            #pragma unroll
            for (int mi = 0; mi < 8; ++mi) {
                int row = wr * 128 + mi * 16 + l16;
                int ch  = (kk * 4 + quad) ^ (row & 7);
                af[mi] = *(const bf16x8*)&aL[row * 64 + ch * 8];
            }
            #pragma unroll
            for (int ni = 0; ni < NI; ++ni) {
                int row = wc * (NI * 16) + ni * 16 + l16;
                int ch  = (kk * 4 + quad) ^ (row & 7);
                bfr[ni] = *(const bf16x8*)&bL[row * 64 + ch * 8];
            }
            #pragma unroll
            for (int mi = 0; mi < 8; ++mi)
                #pragma unroll
                for (int ni = 0; ni < NI; ++ni)
                    acc[mi][ni] = __builtin_amdgcn_mfma_f32_16x16x32_bf16(af[mi], bfr[ni], acc[mi][ni], 0, 0, 0);
        }
        vm_wait0();    // next tile landed (issued ~2000cy ago -> near-free)
        bar();
    }

    #pragma unroll
    for (int mi = 0; mi < 8; ++mi)
        #pragma unroll
        for (int ni = 0; ni < NI; ++ni)
            #pragma unroll
            for (int r = 0; r < 4; ++r) {
                int row = m0 + wr * 128 + mi * 16 + quad * 4 + r;   // C/D: row = quad*4+reg
                int col = n0 + wc * (NI * 16) + ni * 16 + l16;      //      col = lane&15
                C[(size_t)row * N + col] = (OutT)acc[mi][ni][r];
            }
}

// ---------------- RoPE + head-major scatter; Q pre-scaled by 0.125*log2(e) ----------------
// Vectorized: 192 threads/token, one bf16x8 load + float4 cos/sin + bf16x8 store per thread.
__global__ void k_rope(const bf16* __restrict__ qkv, const float* __restrict__ cosg,
                       const float* __restrict__ sing, bf16* __restrict__ qd, bf16* __restrict__ kd) {
    int token = blockIdx.x;
    int b = token >> 10, s = token & 1023;
    int t = threadIdx.x;                    // 0..191
    int hh = t >> 3, i8 = t & 7;            // head slot, 8-elem chunk (4 rope pairs)
    float4 c4 = *(const float4*)&cosg[s * 32 + i8 * 4];
    float4 s4 = *(const float4*)&sing[s * 32 + i8 * 4];
    int srcBase, dstBase;
    bf16* dst;
    float sf;
    if (hh < 16) {
        srcBase = token * 2048 + hh * 64;
        dstBase = ((b * NH_ + hh) * S_ + s) * 64;
        dst = qd;
        sf = 0.180336879f;                  // 0.125 * log2(e) folded into Q
    } else {
        int h = hh - 16;
        srcBase = token * 2048 + 1024 + h * 64;
        dstBase = ((b * NKV_ + h) * S_ + s) * 64;
        dst = kd;
        sf = 1.0f;
    }
    bf16x8 v = *(const bf16x8*)&qkv[srcBase + i8 * 8];
    const float cc[4] = { c4.x, c4.y, c4.z, c4.w };
    const float ss[4] = { s4.x, s4.y, s4.z, s4.w };
    bf16x8 o;
    #pragma unroll
    for (int j = 0; j < 4; ++j) {
        float e  = (float)v[2 * j];
        float od = (float)v[2 * j + 1];
        o[2 * j]     = (bf16)(sf * (e * cc[j] - od * ss[j]));
        o[2 * j + 1] = (bf16)(sf * (e * ss[j] + od * cc[j]));
    }
    *(bf16x8*)&dst[dstBase + i8 * 8] = o;
}

// ---------------- V transpose: qkv v-part -> vT[b][hkv][d][s'], s' PRE-PERMUTED ----------------
__global__ void k_vtrans(const bf16* __restrict__ qkv, bf16* __restrict__ vt) {
    __shared__ __align__(16) bf16 tile[64 * 72];
    int bid = blockIdx.x;
    int st = bid & 15;
    int h  = (bid >> 4) & 7;
    int b  = bid >> 7;
    int s0 = st * 64;
    int t = threadIdx.x;
    #pragma unroll
    for (int it = 0; it < 2; ++it) {
        int ci = it * 256 + t;
        int r = ci >> 3, c = ci & 7;           // r = s, c = d-chunk
        *(uint4*)&tile[r * 72 + c * 8] =
            *(const uint4*)&qkv[(size_t)(b * S_ + s0 + r) * 2048 + 1536 + h * 64 + c * 8];
    }
    __syncthreads();
    #pragma unroll
    for (int it = 0; it < 2; ++it) {
        int ci = it * 256 + t;
        int d = ci >> 3, sc = ci & 7;
        int g = sc >> 2, q4 = sc & 3;          // internal chunk -> (32-group, quad)
        bf16x8 v;
        #pragma unroll
        for (int j = 0; j < 8; ++j) {
            int s_ext = g * 32 + q4 * 4 + (j & 3) + 16 * (j >> 2);
            v[j] = tile[s_ext * 72 + d];
        }
        *(bf16x8*)&vt[(size_t)((b * NKV_ + h) * 64 + d) * S_ + s0 + sc * 8] = v;
    }
}

// ---------------- flash attention, block-causal (BLK_SIZE=8), no-max softmax ----------------
// Same math as previous round; staging restructured to double-buffered K/V LDS
// with issue-early gll16 + one raw barrier per unit (counted-vmcnt pattern):
// the next unit's loads fly under this unit's QK^T/softmax/PV (~400cy), removing
// the per-unit stage-latency stall that the old sync;stage;sync exposed 17x.
__global__ __launch_bounds__(256) void k_attn(const bf16* __restrict__ q, const bf16* __restrict__ k,
                                              const bf16* __restrict__ vt, bf16* __restrict__ out) {
    __shared__ __align__(16) bf16 kt[2 * 64 * 64];
    __shared__ __align__(16) bf16 vtt[2 * 64 * 64];
    int bid = blockIdx.x;
    int pi = bid & 7;                       // q-tile pair (pi, 15-pi)
    int h  = (bid >> 3) & 15;
    int b  = bid >> 7;
    int qtA = pi, qtB = 15 - pi;
    int hkv = h >> 1;                       // jnp.repeat: q-head h -> kv head h/2
    int t = threadIdx.x;
    int w = t >> 6, lane = t & 63, quad = lane >> 4, l16 = lane & 15;

    // Q frags for both tiles (B operand of S^T mfma): lane n=l16 -> q row qw+l16
    const bf16* qh = q + (size_t)(b * NH_ + h) * S_ * 64;
    int qwA = qtA * 64 + w * 16, qwB = qtB * 64 + w * 16;
    const bf16* qbA = qh + (size_t)(qwA + l16) * 64;
    const bf16* qbB = qh + (size_t)(qwB + l16) * 64;
    bf16x8 qfA0 = *(const bf16x8*)(qbA + quad * 8);
    bf16x8 qfA1 = *(const bf16x8*)(qbA + 32 + quad * 8);
    bf16x8 qfB0 = *(const bf16x8*)(qbB + quad * 8);
    bf16x8 qfB1 = *(const bf16x8*)(qbB + 32 + quad * 8);

    const bf16* kg = k  + (size_t)(b * NKV_ + hkv) * S_ * 64;
    const bf16* vg = vt + (size_t)(b * NKV_ + hkv) * 64 * S_;

    const int sr0 = t >> 3;                 // staging row 0..31 (+32 for it=1)
    const int cs  = t & 7;                  // staging swizzled chunk slot

    auto stage = [&](int k0, int buf) {
        #pragma unroll
        for (int it = 0; it < 2; ++it) {
            int r  = sr0 + it * 32;
            int cg = cs ^ (r & 7);          // slot cs holds global chunk cs^(r&7)
            int ci = it * 256 + t;
            gll16(kg + (size_t)(k0 + r) * 64 + cg * 8, kt  + buf * 4096 + ci * 8);
            gll16(vg + (size_t)r * S_ + k0 + cg * 8,   vtt + buf * 4096 + ci * 8);
        }
    };

    const bf16 one = (bf16)1.0f;
    const bf16x8 vones = { one, one, one, one, one, one, one, one };

    f32x4 o[4] = {};        // PV C-layout: row q=quad*4+r, col d=dc*16+l16
    f32x4 ol = {};          // ones-column: ol[r] = row-sum of P for q=quad*4+r
    bf16x8 qf0 = qfA0, qf1 = qfA1;
    int qw = qwA;

    auto epilogue = [&]() {
        #pragma unroll
        for (int r = 0; r < 4; ++r) {
            float invl = 1.0f / ol[r];
            #pragma unroll
            for (int dc = 0; dc < 4; ++dc) {
                int row = qw + quad * 4 + r;
                int col = h * 64 + dc * 16 + l16;
                out[(size_t)(b * S_ + row) * 1024 + col] = (bf16)(o[dc][r] * invl);
            }
        }
    };

    const int NU = 17;                      // (qtA+1) + (qtB+1) == 17 always
    stage(0, 0);
    vm_wait0();
    bar();

    for (int u = 0; u < NU; ++u) {
        const int buf = u & 1;
        if (u + 1 < NU) {                   // issue-early: next unit under this unit's compute
            int un   = u + 1;
            int ktiN = (un > qtA) ? (un - qtA - 1) : un;
            stage(ktiN * 64, buf ^ 1);
        }
        int kti = (u > qtA) ? (u - qtA - 1) : u;
        int k0  = kti * 64;
        const bf16* ktb = kt  + buf * 4096;
        const bf16* vtb = vtt + buf * 4096;

        f32x4 sc[4] = {};
        #pragma unroll
        for (int kk = 0; kk < 2; ++kk)
            #pragma unroll
            for (int f = 0; f < 4; ++f) {
                int row = f * 16 + l16;
                int ch  = (kk * 4 + quad) ^ (row & 7);
                bf16x8 af = *(const bf16x8*)&ktb[row * 64 + ch * 8];
                sc[f] = __builtin_amdgcn_mfma_f32_16x16x32_bf16(af, kk ? qf1 : qf0, sc[f], 0, 0, 0);
            }

        // p = exp2(sc) directly (Q pre-scaled); masked -> 0. No running max.
        bool diag = (u == qtA) || (u == NU - 1);    // last tile of each phase
        int klim = ((qw + l16) & ~7) + 8;           // block-causal, BLK=8
        float p[4][4];
        #pragma unroll
        for (int f = 0; f < 4; ++f)
            #pragma unroll
            for (int r = 0; r < 4; ++r) {
                float pv = exp2f(sc[f][r]);
                if (diag && (k0 + f * 16 + quad * 4 + r >= klim)) pv = 0.f;
                p[f][r] = pv;
            }

        // P A-frags: internal k=quad*8+j <-> external k' = kk*32 + quad*4+(j&3)+16*(j>>2)
        bf16x8 pa0, pa1;
        #pragma unroll
        for (int j = 0; j < 4; ++j) {
            pa0[j]     = (bf16)p[0][j];
            pa0[j + 4] = (bf16)p[1][j];
            pa1[j]     = (bf16)p[2][j];
            pa1[j + 4] = (bf16)p[3][j];
        }

        // Row sums via ones-column MFMA (replaces lsum adds + epilogue shuffles)
        ol = __builtin_amdgcn_mfma_f32_16x16x32_bf16(pa0, vones, ol, 0, 0, 0);
        ol = __builtin_amdgcn_mfma_f32_16x16x32_bf16(pa1, vones, ol, 0, 0, 0);

        // PV: V pre-permuted in global -> single swizzled b128 per B-frag (same as K)
        #pragma unroll
        for (int dc = 0; dc < 4; ++dc) {
            int row = dc * 16 + l16;
            #pragma unroll
            for (int kk = 0; kk < 2; ++kk) {
                int ch = (kk * 4 + quad) ^ (row & 7);
                bf16x8 vb = *(const bf16x8*)&vtb[row * 64 + ch * 8];
                o[dc] = __builtin_amdgcn_mfma_f32_16x16x32_bf16(kk ? pa1 : pa0, vb, o[dc], 0, 0, 0);
            }
        }

        if (u == qtA) {                     // phase A done: write it out, reset for B
            epilogue();
            #pragma unroll
            for (int dc = 0; dc < 4; ++dc) o[dc] = f32x4{0.f, 0.f, 0.f, 0.f};
            ol = f32x4{0.f, 0.f, 0.f, 0.f};
            qf0 = qfB0; qf1 = qfB1; qw = qwB;
        }

        vm_wait0();    // next unit's K/V landed (issued before compute -> mostly free)
        bar();
    }
    epilogue();                             // phase B
}

// ---------------- launch ----------------
extern "C" void kernel_launch(void* const* d_in, const int* in_sizes, int n_in,
                              void* d_out, int out_size, void* d_ws, size_t ws_size,
                              hipStream_t stream) {
    const float* x  = (const float*)d_in[0];
    const float* wq = (const float*)d_in[1];
    const float* wk = (const float*)d_in[2];
    const float* wv = (const float*)d_in[3];
    const float* wo = (const float*)d_in[4];
    const float* fc = (const float*)d_in[5];
    const float* fs = (const float*)d_in[6];
    (void)in_sizes; (void)n_in; (void)out_size; (void)ws_size;

    char* ws = (char*)d_ws;
    bf16* xb    = (bf16*)(ws);                          // 16 MB, reused as q after GEMM1
    bf16* wqkvT = (bf16*)(ws + (16u << 20));            //  4 MB  [2048][1024]
    bf16* woT   = (bf16*)(ws + (20u << 20));            //  2 MB  [1024][1024]
    bf16* qkvb  = (bf16*)(ws + (22u << 20));            // 32 MB  [8192][2048], reused as attn out
    bf16* kb    = (bf16*)(ws + (54u << 20));            //  8 MB  [8][8][1024][64]
    bf16* vtb   = (bf16*)(ws + (62u << 20));            //  8 MB  [8][8][64][1024]  (70 MB total)
    bf16* qb    = xb;
    bf16* attnb = qkvb;

    k_cvt_bf16<<<dim3(8192), dim3(256), 0, stream>>>(x, xb, (M_ * D_) / 4);
    k_transpose_all<<<dim3(48, 16), dim3(256), 0, stream>>>(wq, wk, wv, wo, wqkvT, woT);

    // GEMM1: [8192,1024] x [2048,1024]^T -> 256x256 tiles, grid 8x32 = 256 wgs (1/CU)
    k_gemm256<bf16, 256><<<dim3(8, 32), dim3(512), 0, stream>>>(xb, wqkvT, qkvb, M_, 2048, 1024);

    k_rope<<<dim3(8192), dim3(192), 0, stream>>>(qkvb, fc, fs, qb, kb);
    k_vtrans<<<dim3(1024), dim3(256), 0, stream>>>(qkvb, vtb);

    k_attn<<<dim3(1024), dim3(256), 0, stream>>>(qb, kb, vtb, attnb);

    // GEMM2: [8192,1024] x [1024,1024]^T -> 256x128 tiles, grid 8x32 = 256 wgs (1/CU)
    k_gemm256<float, 128><<<dim3(8, 32), dim3(512), 0, stream>>>(attnb, woT, (float*)d_out, M_, 1024, 1024);
}

// Round 2
// 207.114 us; speedup vs baseline: 1.1145x; 1.0639x over previous
//
#include <hip/hip_runtime.h>
#include <cstdint>
#include <math.h>

#define B_   8
#define S_   1024
#define D_   1024
#define NH_  16
#define NKV_ 8
#define HD_  64
#define M_   (B_*S_)   // 8192 tokens

using bf16   = __bf16;
using bf16x4 = __attribute__((ext_vector_type(4))) __bf16;
using bf16x8 = __attribute__((ext_vector_type(8))) __bf16;
using f32x4  = __attribute__((ext_vector_type(4))) float;

// ---------------- async global->LDS, width 16 (m97 idiom) ----------------
__device__ __forceinline__ void gll16(const bf16* g, const bf16* l) {
    __builtin_amdgcn_global_load_lds(
        (const __attribute__((address_space(1))) unsigned int*)(uintptr_t)g,
        (__attribute__((address_space(3))) unsigned int*)(uintptr_t)l,
        16, 0, 0);
}

__device__ __forceinline__ void vm_wait0()  { asm volatile("s_waitcnt vmcnt(0)" ::: "memory"); }
__device__ __forceinline__ void bar()       { __builtin_amdgcn_s_barrier(); asm volatile("" ::: "memory"); }

// ---------------- fused prep1: f32->bf16 cvt (blocks 0..8191) + weight transposes ----------------
__global__ void k_prep1(const float* __restrict__ x,
                        const float* __restrict__ wq, const float* __restrict__ wk,
                        const float* __restrict__ wv, const float* __restrict__ wo,
                        bf16* __restrict__ xb, bf16* __restrict__ wqkvT, bf16* __restrict__ woT) {
    __shared__ float tile[64 * 65];
    int bid = blockIdx.x;
    int t = threadIdx.x;
    if (bid < 8192) {                       // cvt: 8192*256 threads cover M_*D_/4 exactly
        int i = bid * 256 + t;
        float4 v = ((const float4*)x)[i];
        bf16x4 o = { (bf16)v.x, (bf16)v.y, (bf16)v.z, (bf16)v.w };
        ((bf16x4*)xb)[i] = o;
        return;
    }
    int b2 = bid - 8192;                    // 0..767 transpose tiles
    int bx = b2 % 48, by = b2 / 48;
    const int R = 1024;
    const float* in; bf16* out; int C, xo;
    if (bx < 16)      { in = wq; out = wqkvT;               C = 1024; xo = bx; }
    else if (bx < 24) { in = wk; out = wqkvT + 1024 * 1024; C = 512;  xo = bx - 16; }
    else if (bx < 32) { in = wv; out = wqkvT + 1536 * 1024; C = 512;  xo = bx - 24; }
    else              { in = wo; out = woT;                 C = 1024; xo = bx - 32; }
    int r0 = by * 64, c0 = xo * 64;
    #pragma unroll
    for (int it = 0; it < 16; ++it) {
        int idx = it * 256 + t;
        int r = idx >> 6, c = idx & 63;
        tile[r * 65 + c] = in[(size_t)(r0 + r) * C + c0 + c];
    }
    __syncthreads();
    #pragma unroll
    for (int it = 0; it < 16; ++it) {
        int idx = it * 256 + t;
        int c = idx >> 6, r = idx & 63;
        out[(size_t)(c0 + c) * R + r0 + r] = (bf16)tile[r * 65 + c];
    }
}

// ---------------- 256-wide GEMM, 4-phase interleaved K-loop ----------------
// Per K-tile: 4 phases {8 ds_read_b128; front-loaded staging (A in p0, B in p1);
// s_barrier; setprio(1) + 16 MFMA + setprio(0); s_barrier}. vmcnt(0) only at the
// tile boundary -- staged loads were issued 3 phases (~600cy) earlier, so the
// drain is covered (T3/T4 + T5 per m196/m218b). Buf is a literal via T+=2 unroll.
// XCD-aware bijective swizzle (nwg=256): each XCD works 4 contiguous m-panels.
template <typename OutT, int BN>
__global__ __launch_bounds__(512, 2) void k_gemm256(const bf16* __restrict__ A,
                                                    const bf16* __restrict__ Bt,
                                                    OutT* __restrict__ C, int M, int N, int K) {
    constexpr int NI = BN / 64;            // n-frags per wave
    constexpr int NB = (BN * 8) / 512;     // B gll16 per thread per tile
    __shared__ __align__(16) bf16 aLds[2 * 256 * 64];
    __shared__ __align__(16) bf16 bLds[2 * BN * 64];
    const int t    = threadIdx.x;
    const int lane = t & 63;
    const int w    = t >> 6;
    const int quad = lane >> 4;
    const int l16  = lane & 15;
    const int wr   = w >> 2;               // 0..1  (M)
    const int wc   = w & 3;                // 0..3  (N)

    // XCD swizzle: bid%8 == XCD -> give each XCD a contiguous grid chunk
    int bid = blockIdx.y * gridDim.x + blockIdx.x;
    int cpx = (gridDim.x * gridDim.y) >> 3;
    int sw  = (bid & 7) * cpx + (bid >> 3);
    int bx  = sw % gridDim.x, by = sw / gridDim.x;
    const int m0 = by * 256;
    const int n0 = bx * BN;

    f32x4 acc[8][NI] = {};

    auto stageA = [&](int kb, int buf) {
        const int k0 = kb << 6;
        #pragma unroll
        for (int it = 0; it < 4; ++it) {   // A: 256 rows x 8 chunks = 2048 / 512thr
            int ci = it * 512 + t;
            int r = ci >> 3, c = ci & 7;
            int cg = c ^ (r & 7);          // slot c of row r holds global chunk c^(r&7)
            gll16(A + (size_t)(m0 + r) * K + k0 + cg * 8, aLds + buf * (256 * 64) + ci * 8);
        }
    };
    auto stageB = [&](int kb, int buf) {
        const int k0 = kb << 6;
        #pragma unroll
        for (int it = 0; it < NB; ++it) {
            int ci = it * 512 + t;
            int r = ci >> 3, c = ci & 7;
            int cg = c ^ (r & 7);
            gll16(Bt + (size_t)(n0 + r) * K + k0 + cg * 8, bLds + buf * (BN * 64) + ci * 8);
        }
    };

    const int NT = K >> 6;

    // phase: stageSel 0=none 1=A 2=B; lastInTile -> vmcnt(0) before closing barrier
    auto phase = [&](int buf, int kk, int mh, int stageSel, int nkb, bool lastInTile) {
        const bf16* aL = aLds + buf * (256 * 64);
        const bf16* bL = bLds + buf * (BN * 64);
        bf16x8 af[4], bfr[NI];
        #pragma unroll
        for (int i = 0; i < 4; ++i) {
            int row = wr * 128 + (mh * 4 + i) * 16 + l16;
            int ch  = (kk * 4 + quad) ^ (row & 7);
            af[i] = *(const bf16x8*)&aL[row * 64 + ch * 8];
        }
        #pragma unroll
        for (int ni = 0; ni < NI; ++ni) {
            int row = wc * (NI * 16) + ni * 16 + l16;
            int ch  = (kk * 4 + quad) ^ (row & 7);
            bfr[ni] = *(const bf16x8*)&bL[row * 64 + ch * 8];
        }
        if (stageSel == 1) stageA(nkb, buf ^ 1);
        else if (stageSel == 2) stageB(nkb, buf ^ 1);
        bar();
        __builtin_amdgcn_s_setprio(1);
        #pragma unroll
        for (int i = 0; i < 4; ++i)
            #pragma unroll
            for (int ni = 0; ni < NI; ++ni)
                acc[mh * 4 + i][ni] = __builtin_amdgcn_mfma_f32_16x16x32_bf16(af[i], bfr[ni], acc[mh * 4 + i][ni], 0, 0, 0);
        __builtin_amdgcn_s_setprio(0);
        if (lastInTile) vm_wait0();
        bar();
    };

    auto doTile = [&](int T, int buf) {
        bool hn = (T + 1 < NT);
        phase(buf, 0, 0, hn ? 1 : 0, T + 1, false);
        phase(buf, 0, 1, hn ? 2 : 0, T + 1, false);
        phase(buf, 1, 0, 0, 0, false);
        phase(buf, 1, 1, 0, 0, true);
    };

    stageA(0, 0); stageB(0, 0);
    vm_wait0();
    bar();
    for (int T = 0; T < NT; T += 2) {      // NT=16: buf literal inside
        doTile(T, 0);
        doTile(T + 1, 1);
    }

    #pragma unroll
    for (int mi = 0; mi < 8; ++mi)
        #pragma unroll
        for (int ni = 0; ni < NI; ++ni)
            #pragma unroll
            for (int r = 0; r < 4; ++r) {
                int row = m0 + wr * 128 + mi * 16 + quad * 4 + r;   // C/D: row = quad*4+reg
                int col = n0 + wc * (NI * 16) + ni * 16 + l16;      //      col = lane&15
                C[(size_t)row * N + col] = (OutT)acc[mi][ni][r];
            }
}

// ---------------- fused prep2: RoPE scatter (blocks 0..8191) + V transpose ----------------
__global__ void k_prep2(const bf16* __restrict__ qkv, const float* __restrict__ cosg,
                        const float* __restrict__ sing, bf16* __restrict__ qd,
                        bf16* __restrict__ kd, bf16* __restrict__ vt) {
    __shared__ __align__(16) bf16 tile[64 * 72];
    int bid = blockIdx.x;
    int t = threadIdx.x;
    if (bid < 8192) {                       // RoPE: 192 active lanes/token
        if (t < 192) {
            int token = bid;
            int b = token >> 10, s = token & 1023;
            int hh = t >> 3, i8 = t & 7;
            float4 c4 = *(const float4*)&cosg[s * 32 + i8 * 4];
            float4 s4 = *(const float4*)&sing[s * 32 + i8 * 4];
            int srcBase, dstBase;
            bf16* dst;
            float sf;
            if (hh < 16) {
                srcBase = token * 2048 + hh * 64;
                dstBase = ((b * NH_ + hh) * S_ + s) * 64;
                dst = qd;
                sf = 0.180336879f;          // 0.125 * log2(e) folded into Q
            } else {
                int h = hh - 16;
                srcBase = token * 2048 + 1024 + h * 64;
                dstBase = ((b * NKV_ + h) * S_ + s) * 64;
                dst = kd;
                sf = 1.0f;
            }
            bf16x8 v = *(const bf16x8*)&qkv[srcBase + i8 * 8];
            const float cc[4] = { c4.x, c4.y, c4.z, c4.w };
            const float ss[4] = { s4.x, s4.y, s4.z, s4.w };
            bf16x8 o;
            #pragma unroll
            for (int j = 0; j < 4; ++j) {
                float e  = (float)v[2 * j];
                float od = (float)v[2 * j + 1];
                o[2 * j]     = (bf16)(sf * (e * cc[j] - od * ss[j]));
                o[2 * j + 1] = (bf16)(sf * (e * ss[j] + od * cc[j]));
            }
            *(bf16x8*)&dst[dstBase + i8 * 8] = o;
        }
        return;
    }
    int b2 = bid - 8192;                    // 0..1023 vtrans tiles
    int st = b2 & 15;
    int h  = (b2 >> 4) & 7;
    int b  = b2 >> 7;
    int s0 = st * 64;
    #pragma unroll
    for (int it = 0; it < 2; ++it) {
        int ci = it * 256 + t;
        int r = ci >> 3, c = ci & 7;           // r = s, c = d-chunk
        *(uint4*)&tile[r * 72 + c * 8] =
            *(const uint4*)&qkv[(size_t)(b * S_ + s0 + r) * 2048 + 1536 + h * 64 + c * 8];
    }
    __syncthreads();
    #pragma unroll
    for (int it = 0; it < 2; ++it) {
        int ci = it * 256 + t;
        int d = ci >> 3, sc = ci & 7;
        int g = sc >> 2, q4 = sc & 3;          // internal chunk -> (32-group, quad)
        bf16x8 v;
        #pragma unroll
        for (int j = 0; j < 8; ++j) {
            int s_ext = g * 32 + q4 * 4 + (j & 3) + 16 * (j >> 2);
            v[j] = tile[s_ext * 72 + d];
        }
        *(bf16x8*)&vt[(size_t)((b * NKV_ + h) * 64 + d) * S_ + s0 + sc * 8] = v;
    }
}

// ---------------- flash attention, per-q-tile blocks, block-causal, no-max softmax ----------------
// Grid 2048 = B*NH*16 q-tiles, big tiles dispatched first (qt = 15 - bid/128) so
// 16-unit blocks start earliest and 1-unit blocks backfill -> 5 blocks/CU resident
// (LDS-capped) vs round-1's grid-capped 4. Unit loop manually unrolled by 2 so the
// LDS buffer index is a literal: all 16 ds_read addresses become loop-invariant
// (hoisted once; buf1 folds into offset immediates), cutting the per-unit VALU that
// capped round 1 at VALUBusy 65 / Mfma 16. Math identical to round 1 (verified).
__global__ __launch_bounds__(256) void k_attn(const bf16* __restrict__ q, const bf16* __restrict__ k,
                                              const bf16* __restrict__ vt, bf16* __restrict__ out) {
    __shared__ __align__(16) bf16 kt[2 * 64 * 64];
    __shared__ __align__(16) bf16 vtt[2 * 64 * 64];
    int bid = blockIdx.x;
    int qt = 15 - (bid >> 7);               // big q-tiles first
    int combo = bid & 127;
    int b = combo >> 4, h = combo & 15;
    int hkv = h >> 1;                       // jnp.repeat: q-head h -> kv head h/2
    int t = threadIdx.x;
    int w = t >> 6, lane = t & 63, quad = lane >> 4, l16 = lane & 15;

    const bf16* qh = q + (size_t)(b * NH_ + h) * S_ * 64;
    int qw = qt * 64 + w * 16;
    const bf16* qb = qh + (size_t)(qw + l16) * 64;
    bf16x8 qf0 = *(const bf16x8*)(qb + quad * 8);
    bf16x8 qf1 = *(const bf16x8*)(qb + 32 + quad * 8);

    const bf16* kg = k  + (size_t)(b * NKV_ + hkv) * S_ * 64;
    const bf16* vg = vt + (size_t)(b * NKV_ + hkv) * 64 * S_;

    const int sr0 = t >> 3;                 // staging row 0..31 (+32 for it=1)
    const int cs  = t & 7;                  // staging swizzled chunk slot

    auto stage = [&](int u, int buf) {
        int k0 = u * 64;
        #pragma unroll
        for (int it = 0; it < 2; ++it) {
            int r  = sr0 + it * 32;
            int cg = cs ^ (r & 7);          // slot cs holds global chunk cs^(r&7)
            int ci = it * 256 + t;
            gll16(kg + (size_t)(k0 + r) * 64 + cg * 8, kt  + buf * 4096 + ci * 8);
            gll16(vg + (size_t)r * S_ + k0 + cg * 8,   vtt + buf * 4096 + ci * 8);
        }
    };

    const bf16 one = (bf16)1.0f;
    const bf16x8 vones = { one, one, one, one, one, one, one, one };

    f32x4 o[4] = {};        // PV C-layout: row q=quad*4+r, col d=dc*16+l16
    f32x4 ol = {};          // ones-column: ol[r] = row-sum of P for q=quad*4+r
    const int klim = ((qw + l16) & ~7) + 8; // block-causal, BLK=8

    auto unit = [&](int u, int buf, bool diag) {
        const bf16* ktb = kt  + buf * 4096;
        const bf16* vtb = vtt + buf * 4096;
        int k0 = u * 64;

        f32x4 sc[4] = {};
        #pragma unroll
        for (int kk = 0; kk < 2; ++kk)
            #pragma unroll
            for (int f = 0; f < 4; ++f) {
                int row = f * 16 + l16;
                int ch  = (kk * 4 + quad) ^ (row & 7);
                bf16x8 af = *(const bf16x8*)&ktb[row * 64 + ch * 8];
                sc[f] = __builtin_amdgcn_mfma_f32_16x16x32_bf16(af, kk ? qf1 : qf0, sc[f], 0, 0, 0);
            }

        // p = exp2(sc) directly (Q pre-scaled); masked -> 0. No running max.
        float p[4][4];
        #pragma unroll
        for (int f = 0; f < 4; ++f)
            #pragma unroll
            for (int r = 0; r < 4; ++r) {
                float pv = __builtin_amdgcn_exp2f(sc[f][r]);
                if (diag && (k0 + f * 16 + quad * 4 + r >= klim)) pv = 0.f;
                p[f][r] = pv;
            }

        // P A-frags: internal k=quad*8+j <-> external k' = kk*32 + quad*4+(j&3)+16*(j>>2)
        bf16x8 pa0, pa1;
        #pragma unroll
        for (int j = 0; j < 4; ++j) {
            pa0[j]     = (bf16)p[0][j];
            pa0[j + 4] = (bf16)p[1][j];
            pa1[j]     = (bf16)p[2][j];
            pa1[j + 4] = (bf16)p[3][j];
        }

        // Row sums via ones-column MFMA
        ol = __builtin_amdgcn_mfma_f32_16x16x32_bf16(pa0, vones, ol, 0, 0, 0);
        ol = __builtin_amdgcn_mfma_f32_16x16x32_bf16(pa1, vones, ol, 0, 0, 0);

        // PV: V pre-permuted in global -> single swizzled b128 per B-frag
        #pragma unroll
        for (int dc = 0; dc < 4; ++dc) {
            int row = dc * 16 + l16;
            #pragma unroll
            for (int kk = 0; kk < 2; ++kk) {
                int ch = (kk * 4 + quad) ^ (row & 7);
                bf16x8 vb = *(const bf16x8*)&vtb[row * 64 + ch * 8];
                o[dc] = __builtin_amdgcn_mfma_f32_16x16x32_bf16(kk ? pa1 : pa0, vb, o[dc], 0, 0, 0);
            }
        }
        vm_wait0();     // next unit's K/V landed (issued before this unit's compute)
        bar();
    };

    const int NU = qt + 1;
    stage(0, 0);
    vm_wait0();
    bar();

    int u = 0;
    for (; u + 2 <= NU; u += 2) {
        stage(u + 1, 1);                    // issue-early under unit u's compute
        unit(u, 0, false);                  // u <= NU-2 here: never diagonal
        if (u + 2 < NU) stage(u + 2, 0);
        unit(u + 1, 1, (u + 1) == NU - 1);
    }
    if (u < NU) unit(u, 0, true);           // odd-NU tail: the diagonal unit

    // epilogue
    #pragma unroll
    for (int r = 0; r < 4; ++r) {
        float invl = 1.0f / ol[r];
        #pragma unroll
        for (int dc = 0; dc < 4; ++dc) {
            int row = qw + quad * 4 + r;
            int col = h * 64 + dc * 16 + l16;
            out[(size_t)(b * S_ + row) * 1024 + col] = (bf16)(o[dc][r] * invl);
        }
    }
}

// ---------------- launch ----------------
extern "C" void kernel_launch(void* const* d_in, const int* in_sizes, int n_in,
                              void* d_out, int out_size, void* d_ws, size_t ws_size,
                              hipStream_t stream) {
    const float* x  = (const float*)d_in[0];
    const float* wq = (const float*)d_in[1];
    const float* wk = (const float*)d_in[2];
    const float* wv = (const float*)d_in[3];
    const float* wo = (const float*)d_in[4];
    const float* fc = (const float*)d_in[5];
    const float* fs = (const float*)d_in[6];
    (void)in_sizes; (void)n_in; (void)out_size; (void)ws_size;

    char* ws = (char*)d_ws;
    bf16* xb    = (bf16*)(ws);                          // 16 MB, reused as q after GEMM1
    bf16* wqkvT = (bf16*)(ws + (16u << 20));            //  4 MB  [2048][1024]
    bf16* woT   = (bf16*)(ws + (20u << 20));            //  2 MB  [1024][1024]
    bf16* qkvb  = (bf16*)(ws + (22u << 20));            // 32 MB  [8192][2048], reused as attn out
    bf16* kb    = (bf16*)(ws + (54u << 20));            //  8 MB  [8][8][1024][64]
    bf16* vtb   = (bf16*)(ws + (62u << 20));            //  8 MB  [8][8][64][1024]  (70 MB total)
    bf16* qb    = xb;
    bf16* attnb = qkvb;

    k_prep1<<<dim3(8960), dim3(256), 0, stream>>>(x, wq, wk, wv, wo, xb, wqkvT, woT);

    // GEMM1: [8192,1024] x [2048,1024]^T -> 256x256 tiles, grid 8x32 = 256 wgs (1/CU)
    k_gemm256<bf16, 256><<<dim3(8, 32), dim3(512), 0, stream>>>(xb, wqkvT, qkvb, M_, 2048, 1024);

    k_prep2<<<dim3(9216), dim3(256), 0, stream>>>(qkvb, fc, fs, qb, kb, vtb);

    // attn: per-q-tile blocks, 2048 wgs, big tiles first
    k_attn<<<dim3(2048), dim3(256), 0, stream>>>(qb, kb, vtb, attnb);

    // GEMM2: [8192,1024] x [1024,1024]^T -> 256x128 tiles, grid 8x32 = 256 wgs (1/CU)
    k_gemm256<float, 128><<<dim3(8, 32), dim3(512), 0, stream>>>(attnb, woT, (float*)d_out, M_, 1024, 1024);
}